// Round 8
// baseline (455.033 us; speedup 1.0000x reference)
//
#include <hip/hip_runtime.h>
#include <math.h>

#define BB 16
#define NN 512
#define HID 32
#define KCYC 3   // (201-1)/100 + 1

#define HALO 16
#define TW 96        // logical tile width (64 + 2*HALO)
#define TWP 97       // LDS pitch: 97 % 32 == 1 -> conflict-free Phase D
#define OT 64

// fast tanh-approx GELU: gelu(v) = v / (1 + exp2(K1*v + K2*v^3))
#define GELU_K1 (-2.302208201f)
#define GELU_K2 (-0.102944244f)

// ---------------------------------------------------------------------------
// LFA map: lfa[b,i,j] = |1 - tau * S(theta1, theta2)|^5
// ---------------------------------------------------------------------------
__global__ __launch_bounds__(256) void lfa_kernel(const float* __restrict__ kernelA,
                                                  float* __restrict__ lfa) {
    int j = blockIdx.x * 256 + threadIdx.x;   // col
    int i = blockIdx.y;                       // row
    int b = blockIdx.z;
    const float* a = kernelA + b * 9;
    float a0 = a[0], a1 = a[1], a2 = a[2], a3 = a[3], a4 = a[4];
    float a5 = a[5], a6 = a[6], a7 = a[7], a8 = a[8];

    const float h = 1.0f / (float)(NN + 1);
    const float twopi_h = 6.283185307179586f * h;
    float th1 = twopi_h * (float)(j - NN / 2);
    float th2 = twopi_h * (float)(i - NN / 2);
    float s1, c1, s2, c2;
    sincosf(th1, &s1, &c1);
    sincosf(th2, &s2, &c2);

    float cpp = c1 * c2 - s1 * s2;
    float spp = s1 * c2 + c1 * s2;
    float cpm = c1 * c2 + s1 * s2;
    float spm = s1 * c2 - c1 * s2;

    float re = a4 + (a3 + a5) * c1 + (a1 + a7) * c2
             + (a0 + a8) * cpp + (a2 + a6) * cpm;
    float im = (a5 - a3) * s1 + (a7 - a1) * s2
             + (a8 - a0) * spp + (a2 - a6) * spm;

    float tau = 0.5f / a4;
    float zre = 1.0f - tau * re;
    float zim = -tau * im;
    float m2 = zre * zre + zim * zim;
    float v = m2 * m2 * sqrtf(m2);    // |z|^5

    lfa[(size_t)b * NN * NN + (size_t)i * NN + j] = v;
}

__device__ __forceinline__ float fast_gelu(float v) {
    float m = v * fmaf(GELU_K2, v * v, GELU_K1);
    float e = __builtin_amdgcn_exp2f(m);
    return v * __builtin_amdgcn_rcpf(1.0f + e);
}

// ---------------------------------------------------------------------------
// One full cycle: 10 Jacobi sweeps (register-resident 12x3 blocks, LDS halo
// exchange only) + fused pointwise-MLP correction (thread-remapped, 1x work).
// Guard-ring LDS tile, all LDS access = base pointer + compile-time immediate
// (round-7: this keeps VGPR at 128 -> 4 waves/SIMD; do NOT disturb).
// LAST variant: additionally corrects the 260-cell perimeter ring [15,81)^2,
// publishes corrected state to LDS, computes r = f - A x_corr over the owned
// 64x64, and block-reduces ||r||^2, ||f||^2 into global atomics -- replacing
// the separate resnorm kernel and the final 16 MB x write.
// ---------------------------------------------------------------------------
template <bool FIRST, bool LAST>
__global__ __launch_bounds__(256) void fused_cycle(
        const float* __restrict__ xin, float* __restrict__ xout,
        const float* __restrict__ f, const float* __restrict__ kernelA,
        const float* __restrict__ lfa,
        const float* __restrict__ W1, const float* __restrict__ b1,
        const float* __restrict__ W2, const float* __restrict__ b2,
        float* __restrict__ racc) {
    __shared__ float sxraw[98 * TWP + 2];
    float* sx = sxraw + TWP + 1;   // logical origin (0,0); row r col c -> sx[r*TWP+c]
    const int tx = threadIdx.x;   // 0..31
    const int ty = threadIdx.y;   // 0..7
    const int t  = ty * 32 + tx;
    const int b  = blockIdx.z;
    const int gy0 = blockIdx.y * OT;
    const int gx0 = blockIdx.x * OT;
    const int goi = gy0 - HALO;
    const int goj = gx0 - HALO;
    const float* fg = f + (size_t)b * NN * NN;
    const float* lfg = lfa + (size_t)b * NN * NN;
    const float* ag = kernelA + b * 9;   // uniform -> s_load
    const float ar0 = ag[0], ar1 = ag[1], ar2 = ag[2], ar3 = ag[3], ar4 = ag[4];
    const float ar5 = ag[5], ar6 = ag[6], ar7 = ag[7], ar8 = ag[8];
    const float tau = 0.5f / ar4;
    // tau-scaled stencil for the sweeps
    const float s0 = tau * ar0, q1 = tau * ar1, q2 = tau * ar2, q3 = tau * ar3;
    const float q4 = tau * ar4, q5 = tau * ar5, q6 = tau * ar6, q7 = tau * ar7;
    const float q8 = tau * ar8;

    // ---- zero the guard ring (top band, shared L/R col guards, bottom band)
    if (t < 98) sxraw[t] = 0.f;                 // logical row -1, col -1..96
    if (t < 96) sxraw[97 + 97 * t] = 0.f;       // col -1 of row t (== col 96 of row t-1)
    if (t < 98) sxraw[9409 + t] = 0.f;          // logical row 96, col -1..96

    // ---- Phase A: tile -> LDS (interior 96x96) ----
    if (FIRST) {
#pragma unroll
        for (int k = 0; k < (TW * TW) / 256; ++k) {
            int idx = t + k * 256;
            int row = idx / TW, col = idx - row * TW;
            sx[row * TWP + col] = 0.f;
        }
    } else {
        const float* xg = xin + (size_t)b * NN * NN;
#pragma unroll
        for (int k = 0; k < (TW * TW) / 256; ++k) {
            int idx = t + k * 256;
            int row = idx / TW, col = idx - row * TW;
            int gi = goi + row, gj = goj + col;
            float v = 0.f;
            if (gi >= 0 && gi < NN && gj >= 0 && gj < NN) v = xg[gi * NN + gj];
            sx[row * TWP + col] = v;
        }
    }

    const int R0 = ty * 12, C0 = tx * 3;

    // single base pointers: all LDS traffic below is base + compile-time imm
    const float* pb  = sx + (R0 - 1) * TWP + (C0 - 1);  // extended-block origin
    float*       pwv = sx + R0 * TWP + C0;              // owned-cell origin

    // masks: cell updates only if tile-interior AND inside global domain
    float vR[12], vC[3];
#pragma unroll
    for (int r = 0; r < 12; ++r) {
        int R = R0 + r, gi = goi + R;
        vR[r] = (R >= 1 && R < TW - 1 && gi >= 0 && gi < NN) ? 1.f : 0.f;
    }
#pragma unroll
    for (int c = 0; c < 3; ++c) {
        int C = C0 + c, gj = goj + C;
        vC[c] = (C >= 1 && C < TW - 1 && gj >= 0 && gj < NN) ? 1.f : 0.f;
    }

    // tau-scaled f for owned cells (0 outside domain)
    float frt[12][3];
#pragma unroll
    for (int r = 0; r < 12; ++r) {
        int gi = goi + R0 + r;
#pragma unroll
        for (int c = 0; c < 3; ++c) {
            int gj = goj + C0 + c;
            frt[r][c] = (gi >= 0 && gi < NN && gj >= 0 && gj < NN)
                            ? tau * fg[gi * NN + gj] : 0.f;
        }
    }

    __syncthreads();   // tile + guards visible

    // ---- Phase B: own cells -> registers ----
    float cur[12][3];
    if (FIRST) {
#pragma unroll
        for (int r = 0; r < 12; ++r) { cur[r][0] = cur[r][1] = cur[r][2] = 0.f; }
    } else {
#pragma unroll
        for (int r = 0; r < 12; ++r) {
            cur[r][0] = pwv[r * TWP];
            cur[r][1] = pwv[r * TWP + 1];
            cur[r][2] = pwv[r * TWP + 2];
        }
    }

    // ---- Phase C: 10 sweeps ----
    for (int s = 0; s < 10; ++s) {
        // halo reads (34), all immediate offsets off pb
        float top0 = pb[0], top1 = pb[1], top2 = pb[2], top3 = pb[3], top4 = pb[4];
        float bot0 = pb[13 * TWP],     bot1 = pb[13 * TWP + 1],
              bot2 = pb[13 * TWP + 2], bot3 = pb[13 * TWP + 3],
              bot4 = pb[13 * TWP + 4];
        float pm0 = top1, pm1v = top2, pm2 = top3;
        float Lm1 = top0, Rm1 = top4;
        float Lc = pb[TWP], Rc = pb[TWP + 4];
#pragma unroll
        for (int r = 0; r < 12; ++r) {
            float n0, n1, n2, Lp, Rp;
            if (r < 11) {
                n0 = cur[r + 1][0]; n1 = cur[r + 1][1]; n2 = cur[r + 1][2];
                Lp = pb[(r + 2) * TWP];
                Rp = pb[(r + 2) * TWP + 4];
            } else {
                n0 = bot1; n1 = bot2; n2 = bot3; Lp = bot0; Rp = bot4;
            }
            float o0 = cur[r][0], o1 = cur[r][1], o2 = cur[r][2];
            // c = 0
            {
                float ax = s0 * Lm1;
                ax = fmaf(q1, pm0, ax); ax = fmaf(q2, pm1v, ax);
                ax = fmaf(q3, Lc, ax);  ax = fmaf(q4, o0, ax);
                ax = fmaf(q5, o1, ax);  ax = fmaf(q6, Lp, ax);
                ax = fmaf(q7, n0, ax);  ax = fmaf(q8, n1, ax);
                cur[r][0] = fmaf(vR[r] * vC[0], frt[r][0] - ax, o0);
            }
            // c = 1
            {
                float ax = s0 * pm0;
                ax = fmaf(q1, pm1v, ax); ax = fmaf(q2, pm2, ax);
                ax = fmaf(q3, o0, ax);   ax = fmaf(q4, o1, ax);
                ax = fmaf(q5, o2, ax);   ax = fmaf(q6, n0, ax);
                ax = fmaf(q7, n1, ax);   ax = fmaf(q8, n2, ax);
                cur[r][1] = fmaf(vR[r] * vC[1], frt[r][1] - ax, o1);
            }
            // c = 2
            {
                float ax = s0 * pm1v;
                ax = fmaf(q1, pm2, ax); ax = fmaf(q2, Rm1, ax);
                ax = fmaf(q3, o1, ax);  ax = fmaf(q4, o2, ax);
                ax = fmaf(q5, Rc, ax);  ax = fmaf(q6, n1, ax);
                ax = fmaf(q7, n2, ax);  ax = fmaf(q8, Rp, ax);
                cur[r][2] = fmaf(vR[r] * vC[2], frt[r][2] - ax, o2);
            }
            pm0 = o0; pm1v = o1; pm2 = o2;
            Lm1 = Lc; Rm1 = Rc; Lc = Lp; Rc = Rp;
        }
        __syncthreads();   // all halo reads done
        if (s < 9) {
            // write border cells (26)
            pwv[0] = cur[0][0]; pwv[1] = cur[0][1]; pwv[2] = cur[0][2];
            pwv[11 * TWP] = cur[11][0]; pwv[11 * TWP + 1] = cur[11][1];
            pwv[11 * TWP + 2] = cur[11][2];
#pragma unroll
            for (int r = 1; r < 11; ++r) {
                pwv[r * TWP] = cur[r][0];
                pwv[r * TWP + 2] = cur[r][2];
            }
        } else {
            // final sweep: publish ALL cells for the correction phase
#pragma unroll
            for (int r = 0; r < 12; ++r) {
                pwv[r * TWP] = cur[r][0];
                pwv[r * TWP + 1] = cur[r][1];
                pwv[r * TWP + 2] = cur[r][2];
            }
        }
        __syncthreads();   // writes visible
    }

    // ---- Phase D(ring), LAST only: corrected values for the perimeter ring
    // [15,81)^2 \ [16,80)^2 (260 cells), computed from x10 BEFORE any publish.
    // Masked (out-of-domain) writes are redirected to dead rows 0..2 of sx.
    float cv0 = 0.f, cv1 = 0.f;
    int wa0 = t, wa1 = t;   // dead-slot defaults (sx rows 0..2, never read later)
    if (LAST) {
        {   // half 0: idx = t (all 256 threads have a ring cell)
            int idx = t;
            int row, col;
            if (idx < 66)       { row = 0;  col = idx; }
            else if (idx < 132) { row = 65; col = idx - 66; }
            else if (idx < 196) { row = idx - 131; col = 0; }
            else                { row = idx - 195; col = 65; }
            int RR = 15 + row, CC = 15 + col;
            int gi = gy0 + row - 1, gj = gx0 + col - 1;
            bool ok = (gi >= 0) && (gi < NN) && (gj >= 0) && (gj < NN);
            const float* pc = sx + RR * TWP + CC;
            float xc = pc[0];
            float ax = ar0 * pc[-TWP - 1];
            ax = fmaf(ar1, pc[-TWP], ax);    ax = fmaf(ar2, pc[-TWP + 1], ax);
            ax = fmaf(ar3, pc[-1], ax);      ax = fmaf(ar4, pc[0], ax);
            ax = fmaf(ar5, pc[1], ax);       ax = fmaf(ar6, pc[TWP - 1], ax);
            ax = fmaf(ar7, pc[TWP], ax);     ax = fmaf(ar8, pc[TWP + 1], ax);
            float ffv = 0.f, llv = 0.f;
            if (ok) {
                size_t gidx = (size_t)gi * NN + gj;
                ffv = fg[gidx]; llv = lfg[gidx];
            }
            float rres = ffv - ax;
            float a1 = 0.f;
            for (int hh = 0; hh < HID; ++hh) {
                float v = fmaf(W1[2 * hh], llv, fmaf(W1[2 * hh + 1], rres, b1[hh]));
                a1 = fmaf(W2[hh], fast_gelu(v), a1);
            }
            cv0 = xc + a1 + b2[0];
            if (ok) wa0 = RR * TWP + CC;
        }
        if (t < 4) {   // half 1: idx = 256 + t (4 leftover ring cells)
            int idx = 256 + t;
            int row = idx - 195, col = 65;
            int RR = 15 + row, CC = 15 + col;
            int gi = gy0 + row - 1, gj = gx0 + col - 1;
            bool ok = (gi >= 0) && (gi < NN) && (gj >= 0) && (gj < NN);
            const float* pc = sx + RR * TWP + CC;
            float xc = pc[0];
            float ax = ar0 * pc[-TWP - 1];
            ax = fmaf(ar1, pc[-TWP], ax);    ax = fmaf(ar2, pc[-TWP + 1], ax);
            ax = fmaf(ar3, pc[-1], ax);      ax = fmaf(ar4, pc[0], ax);
            ax = fmaf(ar5, pc[1], ax);       ax = fmaf(ar6, pc[TWP - 1], ax);
            ax = fmaf(ar7, pc[TWP], ax);     ax = fmaf(ar8, pc[TWP + 1], ax);
            float ffv = 0.f, llv = 0.f;
            if (ok) {
                size_t gidx = (size_t)gi * NN + gj;
                ffv = fg[gidx]; llv = lfg[gidx];
            }
            float rres = ffv - ax;
            float a1 = 0.f;
            for (int hh = 0; hh < HID; ++hh) {
                float v = fmaf(W1[2 * hh], llv, fmaf(W1[2 * hh + 1], rres, b1[hh]));
                a1 = fmaf(W2[hh], fast_gelu(v), a1);
            }
            cv1 = xc + a1 + b2[0];
            if (ok) wa1 = RR * TWP + CC;
        }
    }

    // ---- Phase D: remapped correction, exactly 1x MLP work ----
    // thread t -> output row orow = t/4 (0..63), column segment oseg = t%4
    const int orow = t >> 2;
    const int oseg = t & 3;
    const int Rl = HALO + orow;           // 16..79
    const int Cl0 = HALO + oseg * 16;     // 16,32,48,64
    const float* pw = sx + (Rl - 1) * TWP + (Cl0 - 1);   // single base + imm
    float w0[18], w1[18], w2[18];
#pragma unroll
    for (int k = 0; k < 18; ++k) {
        w0[k] = pw[k];
        w1[k] = pw[TWP + k];
        w2[k] = pw[2 * TWP + k];
    }
    const int gi = gy0 + orow;
    const int gjb = gx0 + oseg * 16;
    const float4* f4 = (const float4*)(fg + (size_t)gi * NN + gjb);
    const float4* l4 = (const float4*)(lfg + (size_t)gi * NN + gjb);
    float fv[16], lv[16];
#pragma unroll
    for (int q = 0; q < 4; ++q) {
        float4 fq = f4[q], lq = l4[q];
        fv[q * 4] = fq.x; fv[q * 4 + 1] = fq.y; fv[q * 4 + 2] = fq.z; fv[q * 4 + 3] = fq.w;
        lv[q * 4] = lq.x; lv[q * 4 + 1] = lq.y; lv[q * 4 + 2] = lq.z; lv[q * 4 + 3] = lq.w;
    }
    float rv[16];
#pragma unroll
    for (int k = 0; k < 16; ++k) {
        float ax = ar0 * w0[k];
        ax = fmaf(ar1, w0[k + 1], ax); ax = fmaf(ar2, w0[k + 2], ax);
        ax = fmaf(ar3, w1[k], ax);     ax = fmaf(ar4, w1[k + 1], ax);
        ax = fmaf(ar5, w1[k + 2], ax); ax = fmaf(ar6, w2[k], ax);
        ax = fmaf(ar7, w2[k + 1], ax); ax = fmaf(ar8, w2[k + 2], ax);
        rv[k] = fv[k] - ax;
    }
    float acc[16];
#pragma unroll
    for (int k = 0; k < 16; ++k) acc[k] = 0.f;
    for (int hh = 0; hh < HID; ++hh) {
        float w1a = W1[2 * hh], w1b = W1[2 * hh + 1], bb = b1[hh], wo = W2[hh];
#pragma unroll
        for (int k = 0; k < 16; ++k) {
            float v = fmaf(w1a, lv[k], fmaf(w1b, rv[k], bb));
            acc[k] = fmaf(wo, fast_gelu(v), acc[k]);
        }
    }
    const float b2v = b2[0];

    if (!LAST) {
        float4* xo4 = (float4*)(xout + (size_t)b * NN * NN + (size_t)gi * NN + gjb);
#pragma unroll
        for (int q = 0; q < 4; ++q) {
            float4 ov;
            ov.x = w1[q * 4 + 1] + acc[q * 4] + b2v;
            ov.y = w1[q * 4 + 2] + acc[q * 4 + 1] + b2v;
            ov.z = w1[q * 4 + 3] + acc[q * 4 + 2] + b2v;
            ov.w = w1[q * 4 + 4] + acc[q * 4 + 3] + b2v;
            xo4[q] = ov;
        }
    } else {
        // ---- Phase E: publish corrected state to LDS, then residual norm ----
        __syncthreads();   // all x10 reads (interior + ring) done
        float* pwr = sx + Rl * TWP + Cl0;
#pragma unroll
        for (int k = 0; k < 16; ++k) pwr[k] = w1[k + 1] + acc[k] + b2v;
        sx[wa0] = cv0;
        if (t < 4) sx[wa1] = cv1;
        __syncthreads();   // corrected tile visible

        float u0[18], u1[18], u2[18];
#pragma unroll
        for (int k = 0; k < 18; ++k) {
            u0[k] = pw[k];
            u1[k] = pw[TWP + k];
            u2[k] = pw[2 * TWP + k];
        }
        float rrs = 0.f, ffs = 0.f;
#pragma unroll
        for (int k = 0; k < 16; ++k) {
            float ax = ar0 * u0[k];
            ax = fmaf(ar1, u0[k + 1], ax); ax = fmaf(ar2, u0[k + 2], ax);
            ax = fmaf(ar3, u1[k], ax);     ax = fmaf(ar4, u1[k + 1], ax);
            ax = fmaf(ar5, u1[k + 2], ax); ax = fmaf(ar6, u2[k], ax);
            ax = fmaf(ar7, u2[k + 1], ax); ax = fmaf(ar8, u2[k + 2], ax);
            float rres = fv[k] - ax;
            rrs = fmaf(rres, rres, rrs);
            ffs = fmaf(fv[k], fv[k], ffs);
        }
#pragma unroll
        for (int off = 32; off > 0; off >>= 1) {
            rrs += __shfl_down(rrs, off, 64);
            ffs += __shfl_down(ffs, off, 64);
        }
        __shared__ float sr[4], sf[4];
        int wave = t >> 6;
        if ((t & 63) == 0) { sr[wave] = rrs; sf[wave] = ffs; }
        __syncthreads();
        if (t == 0) {
            atomicAdd(&racc[0], sr[0] + sr[1] + sr[2] + sr[3]);
            atomicAdd(&racc[1], sf[0] + sf[1] + sf[2] + sf[3]);
        }
    }
}

__global__ void finalize_kernel(const float* __restrict__ acc, float* __restrict__ out) {
    out[0] = sqrtf(acc[0] / acc[1]);
}

// ---------------------------------------------------------------------------
extern "C" void kernel_launch(void* const* d_in, const int* in_sizes, int n_in,
                              void* d_out, int out_size, void* d_ws, size_t ws_size,
                              hipStream_t stream) {
    const float* f  = (const float*)d_in[0];
    const float* kA = (const float*)d_in[1];
    float*       u  = (float*)d_in[2];   // pristine zeros each launch; used as scratch
    const float* W1 = (const float*)d_in[3];
    const float* b1 = (const float*)d_in[4];
    const float* W2 = (const float*)d_in[5];
    const float* b2 = (const float*)d_in[6];
    float* out = (float*)d_out;

    char* ws = (char*)d_ws;
    float* acc = (float*)ws;                                     // 8 B
    float* xB  = (float*)(ws + 256);                             // 16 MiB
    float* lfa = (float*)(ws + 256 + (size_t)BB * NN * NN * 4);  // 16 MiB

    hipMemsetAsync(acc, 0, 2 * sizeof(float), stream);

    lfa_kernel<<<dim3(NN / 256, NN, BB), 256, 0, stream>>>(kA, lfa);

    dim3 jblk(32, 8);
    dim3 jgrd(NN / OT, NN / OT, BB);

    // cycle 1 (x = 0), cycle 2, cycle 3 (+fused residual norm)
    fused_cycle<true, false><<<jgrd, jblk, 0, stream>>>(u, xB, f, kA, lfa, W1, b1, W2, b2, acc);
    fused_cycle<false, false><<<jgrd, jblk, 0, stream>>>(xB, u, f, kA, lfa, W1, b1, W2, b2, acc);
    fused_cycle<false, true><<<jgrd, jblk, 0, stream>>>(u, xB, f, kA, lfa, W1, b1, W2, b2, acc);

    finalize_kernel<<<1, 1, 0, stream>>>(acc, out);
}